// Round 2
// baseline (464.912 us; speedup 1.0000x reference)
//
#include <hip/hip_runtime.h>
#include <hip/hip_bf16.h>

#define BATCH   16384
#define NF      26
#define EDIM    32
#define DIN     832     // NF*EDIM
#define H1D     256
#define H2D     128
#define VOCAB   100000
#define BN_EPS  1e-5f

typedef float  f32x4  __attribute__((ext_vector_type(4)));
typedef __bf16 bf16x8 __attribute__((ext_vector_type(8)));

// workspace layout (bytes)
#define WS_X      0                  // bf16 [BATCH][DIN]        27,262,976
#define WS_Y1     27262976           // f32  [BATCH][H1D]        16,777,216
#define WS_Y2     44040192           // f32  [BATCH][H2D]         8,388,608
#define WS_FM     52428800           // f32  [BATCH]                 65,536
#define WS_W1T    52494336           // bf16 [H1D][DIN]             425,984
#define WS_W2T    52920320           // bf16 [H2D][H1D]              65,536
#define WS_S1     52985856           // f32  [2][H1D]                 2,048
#define WS_S2     52987904           // f32  [2][H2D]                 1,024

// ---------------------------------------------------------------------------
// Convert W1 -> bf16 W1^T [256][832], W2 -> bf16 W2^T [128][256]
__global__ __launch_bounds__(256) void k_convert(const float* __restrict__ W1,
                                                 const float* __restrict__ W2,
                                                 __bf16* __restrict__ W1T,
                                                 __bf16* __restrict__ W2T) {
  int i = blockIdx.x * 256 + threadIdx.x;
  if (i < DIN * H1D) {                // read coalesced, scatter 2B writes
    int c = i & (H1D - 1);
    int k = i >> 8;
    W1T[c * DIN + k] = (__bf16)W1[i];
  }
  int j = i - DIN * H1D;
  if (j >= 0 && j < H1D * H2D) {
    int c = j & (H2D - 1);
    int k = j >> 7;
    W2T[c * H1D + k] = (__bf16)W2[j];
  }
}

// ---------------------------------------------------------------------------
// Gather embeddings -> X (bf16), compute FM logit per row.
// 32 lanes per row (lane d = embedding dim), 2 rows/wave, 8 rows/block.
__global__ __launch_bounds__(256) void k_gather_fm(
    const int* __restrict__ xc, const float* __restrict__ lin,
    const float* __restrict__ lat, const float* __restrict__ bias,
    __bf16* __restrict__ X, float* __restrict__ fm) {
  const int tid  = threadIdx.x;
  const int lane = tid & 63;
  const int wv   = tid >> 6;
  const int sub  = lane >> 5;
  const int d    = lane & 31;
  const int row  = blockIdx.x * 8 + wv * 2 + sub;

  int myidx = 0;
  float linv = 0.f;
  if (d < NF) {
    myidx = xc[row * NF + d];
    linv  = lin[(size_t)d * VOCAB + myidx];
  }

  float s = 0.f, ssq = 0.f;
  __bf16* xrow = X + (size_t)row * DIN;
  #pragma unroll
  for (int f = 0; f < NF; ++f) {
    int idx = __shfl(myidx, f, 32);
    float v = lat[((size_t)f * VOCAB + idx) * EDIM + d];
    s += v; ssq += v * v;
    xrow[f * EDIM + d] = (__bf16)v;
  }
  float sq = s * s;
  #pragma unroll
  for (int off = 16; off > 0; off >>= 1) {
    sq   += __shfl_down(sq,   off, 32);
    ssq  += __shfl_down(ssq,  off, 32);
    linv += __shfl_down(linv, off, 32);
  }
  if (d == 0) fm[row] = linv + 0.5f * (sq - ssq) + bias[0];
}

// ---------------------------------------------------------------------------
// GEMM1: Y1 = X(bf16) @ W1 (b1 cancels in BatchNorm).  Fused BN batch stats.
// Block: 256 thr (4 waves). Tile 128(M) x 64(N). K=832 staged in 2 LDS chunks.
// LDS row stride = 896 B (56 slots, multiple of 8) so the XOR swizzle
// slot^= (c&7) stays inside the row (52 data slots + 4 pad) — G4.
#define G1_STRIDE 896
__global__ __launch_bounds__(256) void k_gemm1(
    const __bf16* __restrict__ X, const __bf16* __restrict__ W1T,
    float* __restrict__ Y1, float* __restrict__ stats1) {
  __shared__ char  ldsW[64 * G1_STRIDE];   // 57,344 B
  __shared__ float redsum[64], redsq[64];

  const int tid  = threadIdx.x;
  const int lane = tid & 63;
  const int wv   = tid >> 6;
  const int mb   = blockIdx.x >> 2;
  const int nb   = blockIdx.x & 3;
  const int l15  = lane & 15;
  const int lq   = lane >> 4;

  f32x4 acc[2][4] = {};
  const int rowbase = mb * 128 + wv * 32;

  for (int ch = 0; ch < 2; ++ch) {
    __syncthreads();
    // stage W1T cols [nb*64,+64), k [ch*416,+416) with XOR swizzle (G4)
    #pragma unroll
    for (int it = 0; it < 13; ++it) {
      int lid = it * 256 + tid;          // 0..3327
      int c   = lid / 52;
      int kc  = lid - c * 52;
      const uint4* src = (const uint4*)(W1T + (size_t)(nb * 64 + c) * DIN + ch * 416);
      int byte = (c * G1_STRIDE + kc * 16) ^ ((c & 7) << 4);
      *(uint4*)(ldsW + byte) = src[kc];
    }
    __syncthreads();

    for (int kk = 0; kk < 13; ++kk) {
      const int kloc = kk * 32 + lq * 8;      // k within chunk
      bf16x8 a[2];
      #pragma unroll
      for (int i = 0; i < 2; ++i)
        a[i] = *(const bf16x8*)(X + (size_t)(rowbase + i * 16 + l15) * DIN
                                  + ch * 416 + kloc);
      #pragma unroll
      for (int j = 0; j < 4; ++j) {
        int c = j * 16 + l15;
        int byte = (c * G1_STRIDE + (kloc << 1)) ^ ((c & 7) << 4);
        bf16x8 b = *(const bf16x8*)(ldsW + byte);
        acc[0][j] = __builtin_amdgcn_mfma_f32_16x16x32_bf16(a[0], b, acc[0][j], 0, 0, 0);
        acc[1][j] = __builtin_amdgcn_mfma_f32_16x16x32_bf16(a[1], b, acc[1][j], 0, 0, 0);
      }
    }
  }

  // epilogue: write Y1 (C layout: col=lane&15, row=(lane>>4)*4+reg — m89)
  const int colbase = nb * 64;
  #pragma unroll
  for (int i = 0; i < 2; ++i) {
    int r0 = rowbase + i * 16 + lq * 4;
    #pragma unroll
    for (int j = 0; j < 4; ++j) {
      int c = colbase + j * 16 + l15;
      #pragma unroll
      for (int r = 0; r < 4; ++r)
        Y1[(size_t)(r0 + r) * H1D + c] = acc[i][j][r];
    }
  }
  // BN batch statistics (sum, sumsq per column)
  __syncthreads();
  if (tid < 64) { redsum[tid] = 0.f; redsq[tid] = 0.f; }
  __syncthreads();
  #pragma unroll
  for (int j = 0; j < 4; ++j) {
    float s = 0.f, q = 0.f;
    #pragma unroll
    for (int i = 0; i < 2; ++i)
      #pragma unroll
      for (int r = 0; r < 4; ++r) { float v = acc[i][j][r]; s += v; q += v * v; }
    atomicAdd(&redsum[j * 16 + l15], s);
    atomicAdd(&redsq [j * 16 + l15], q);
  }
  __syncthreads();
  if (tid < 64) {
    atomicAdd(&stats1[colbase + tid],        redsum[tid]);
    atomicAdd(&stats1[H1D + colbase + tid],  redsq[tid]);
  }
}

// ---------------------------------------------------------------------------
// GEMM2: Y2 = relu(BN1(Y1)) @ W2, BN1 fused into A-load. Fused BN2 stats.
// (32 slots/row = multiple of 8, so XOR swizzle is closed — no padding needed)
__global__ __launch_bounds__(256) void k_gemm2(
    const float* __restrict__ Y1, const __bf16* __restrict__ W2T,
    const float* __restrict__ stats1, const float* __restrict__ g1,
    const float* __restrict__ be1,
    float* __restrict__ Y2, float* __restrict__ stats2) {
  __shared__ char  ldsW[64 * 512];      // 64 cols x 256 k x 2B
  __shared__ float scL[H1D], shL[H1D];
  __shared__ float redsum[64], redsq[64];

  const int tid  = threadIdx.x;
  const int lane = tid & 63;
  const int wv   = tid >> 6;
  const int mb   = blockIdx.x >> 1;
  const int nb   = blockIdx.x & 1;
  const int l15  = lane & 15;
  const int lq   = lane >> 4;

  {  // BN1 affine params per k (column of Y1)
    float s = stats1[tid], q = stats1[H1D + tid];
    float m = s * (1.f / BATCH);
    float v = q * (1.f / BATCH) - m * m;
    float sc = g1[tid] * rsqrtf(v + BN_EPS);
    scL[tid] = sc;
    shL[tid] = be1[tid] - m * sc;
  }
  #pragma unroll
  for (int it = 0; it < 8; ++it) {
    int lid = it * 256 + tid;
    int c   = lid >> 5;
    int kc  = lid & 31;
    const uint4* src = (const uint4*)(W2T + (size_t)(nb * 64 + c) * H1D);
    int byte = (c * 512 + kc * 16) ^ ((c & 7) << 4);
    *(uint4*)(ldsW + byte) = src[kc];
  }
  __syncthreads();

  f32x4 acc[2][4] = {};
  const int rowbase = mb * 128 + wv * 32;

  for (int kk = 0; kk < 8; ++kk) {
    const int k0 = kk * 32 + lq * 8;
    f32x4 sc0 = *(const f32x4*)&scL[k0];
    f32x4 sc1 = *(const f32x4*)&scL[k0 + 4];
    f32x4 sh0 = *(const f32x4*)&shL[k0];
    f32x4 sh1 = *(const f32x4*)&shL[k0 + 4];
    bf16x8 a[2];
    #pragma unroll
    for (int i = 0; i < 2; ++i) {
      const f32x4* yp = (const f32x4*)(Y1 + (size_t)(rowbase + i * 16 + l15) * H1D + k0);
      f32x4 y0 = yp[0], y1 = yp[1];
      bf16x8 av;
      #pragma unroll
      for (int e = 0; e < 4; ++e) {
        av[e]     = (__bf16)fmaxf(y0[e] * sc0[e] + sh0[e], 0.f);
        av[e + 4] = (__bf16)fmaxf(y1[e] * sc1[e] + sh1[e], 0.f);
      }
      a[i] = av;
    }
    #pragma unroll
    for (int j = 0; j < 4; ++j) {
      int c = j * 16 + l15;
      int byte = (c * 512 + (k0 << 1)) ^ ((c & 7) << 4);
      bf16x8 b = *(const bf16x8*)(ldsW + byte);
      acc[0][j] = __builtin_amdgcn_mfma_f32_16x16x32_bf16(a[0], b, acc[0][j], 0, 0, 0);
      acc[1][j] = __builtin_amdgcn_mfma_f32_16x16x32_bf16(a[1], b, acc[1][j], 0, 0, 0);
    }
  }

  const int colbase = nb * 64;
  #pragma unroll
  for (int i = 0; i < 2; ++i) {
    int r0 = rowbase + i * 16 + lq * 4;
    #pragma unroll
    for (int j = 0; j < 4; ++j) {
      int c = colbase + j * 16 + l15;
      #pragma unroll
      for (int r = 0; r < 4; ++r)
        Y2[(size_t)(r0 + r) * H2D + c] = acc[i][j][r];
    }
  }
  __syncthreads();
  if (tid < 64) { redsum[tid] = 0.f; redsq[tid] = 0.f; }
  __syncthreads();
  #pragma unroll
  for (int j = 0; j < 4; ++j) {
    float s = 0.f, q = 0.f;
    #pragma unroll
    for (int i = 0; i < 2; ++i)
      #pragma unroll
      for (int r = 0; r < 4; ++r) { float v = acc[i][j][r]; s += v; q += v * v; }
    atomicAdd(&redsum[j * 16 + l15], s);
    atomicAdd(&redsq [j * 16 + l15], q);
  }
  __syncthreads();
  if (tid < 64) {
    atomicAdd(&stats2[colbase + tid],        redsum[tid]);
    atomicAdd(&stats2[H2D + colbase + tid],  redsq[tid]);
  }
}

// ---------------------------------------------------------------------------
// Final: out = fm + relu(BN2(Y2)) @ W3 + b3.  1 wave per row-iter, lane=2 cols.
__global__ __launch_bounds__(256) void k_final(
    const float* __restrict__ Y2, const float* __restrict__ stats2,
    const float* __restrict__ g2, const float* __restrict__ be2,
    const float* __restrict__ W3, const float* __restrict__ b3,
    const float* __restrict__ fm, float* __restrict__ out) {
  const int tid  = threadIdx.x;
  const int lane = tid & 63;
  const int wv   = tid >> 6;
  const int k0   = lane * 2;

  float s0 = stats2[k0],     q0 = stats2[H2D + k0];
  float s1 = stats2[k0 + 1], q1 = stats2[H2D + k0 + 1];
  float m0 = s0 * (1.f / BATCH), m1 = s1 * (1.f / BATCH);
  float v0 = q0 * (1.f / BATCH) - m0 * m0;
  float v1 = q1 * (1.f / BATCH) - m1 * m1;
  float sc0 = g2[k0]     * rsqrtf(v0 + BN_EPS);
  float sc1 = g2[k0 + 1] * rsqrtf(v1 + BN_EPS);
  float sh0 = be2[k0]     - m0 * sc0;
  float sh1 = be2[k0 + 1] - m1 * sc1;
  float w30 = W3[k0], w31 = W3[k0 + 1];
  float bb  = b3[0];

  const int rbase = blockIdx.x * 64 + wv * 16;
  for (int it = 0; it < 16; ++it) {
    int row = rbase + it;
    float2 y = *(const float2*)(Y2 + (size_t)row * H2D + k0);
    float h0 = fmaxf(y.x * sc0 + sh0, 0.f);
    float h1 = fmaxf(y.y * sc1 + sh1, 0.f);
    float p  = h0 * w30 + h1 * w31;
    #pragma unroll
    for (int off = 32; off > 0; off >>= 1) p += __shfl_xor(p, off);
    if (lane == 0) out[row] = fm[row] + p + bb;
  }
}

// ---------------------------------------------------------------------------
extern "C" void kernel_launch(void* const* d_in, const int* in_sizes, int n_in,
                              void* d_out, int out_size, void* d_ws, size_t ws_size,
                              hipStream_t stream) {
  const int*   xc   = (const int*)  d_in[0];
  const float* lin  = (const float*)d_in[1];
  const float* lat  = (const float*)d_in[2];
  const float* W1   = (const float*)d_in[3];
  // d_in[4] = b1: cancels inside BatchNorm (mean-subtracted) — unused
  const float* g1   = (const float*)d_in[5];
  const float* be1  = (const float*)d_in[6];
  const float* W2   = (const float*)d_in[7];
  // d_in[8] = b2: cancels — unused
  const float* g2   = (const float*)d_in[9];
  const float* be2  = (const float*)d_in[10];
  const float* W3   = (const float*)d_in[11];
  const float* b3   = (const float*)d_in[12];
  const float* bias = (const float*)d_in[13];

  char* ws = (char*)d_ws;
  __bf16* X   = (__bf16*)(ws + WS_X);
  float*  Y1  = (float*) (ws + WS_Y1);
  float*  Y2  = (float*) (ws + WS_Y2);
  float*  fmv = (float*) (ws + WS_FM);
  __bf16* W1T = (__bf16*)(ws + WS_W1T);
  __bf16* W2T = (__bf16*)(ws + WS_W2T);
  float*  S1  = (float*) (ws + WS_S1);
  float*  S2  = (float*) (ws + WS_S2);
  float*  outp = (float*)d_out;

  // zero BN stats (S1,S2 contiguous: 2*256 + 2*128 floats)
  hipMemsetAsync(S1, 0, (2 * H1D + 2 * H2D) * sizeof(float), stream);

  k_convert  <<<dim3(960),  dim3(256), 0, stream>>>(W1, W2, W1T, W2T);
  k_gather_fm<<<dim3(BATCH / 8), dim3(256), 0, stream>>>(xc, lin, lat, bias, X, fmv);
  k_gemm1    <<<dim3(512),  dim3(256), 0, stream>>>(X, W1T, Y1, S1);
  k_gemm2    <<<dim3(256),  dim3(256), 0, stream>>>(Y1, W2T, S1, g1, be1, Y2, S2);
  k_final    <<<dim3(256),  dim3(256), 0, stream>>>(Y2, S2, g2, be2, W3, b3, fmv, outp);
}

// Round 3
// 456.903 us; speedup vs baseline: 1.0175x; 1.0175x over previous
//
#include <hip/hip_runtime.h>
#include <hip/hip_bf16.h>

#define BATCH   16384
#define NF      26
#define EDIM    32
#define DIN     832     // NF*EDIM
#define H1D     256
#define H2D     128
#define VOCAB   100000
#define BN_EPS  1e-5f

typedef float  f32x4  __attribute__((ext_vector_type(4)));
typedef __bf16 bf16x8 __attribute__((ext_vector_type(8)));

// workspace layout (bytes)
#define WS_X      0                  // bf16 [BATCH][DIN]        27,262,976
#define WS_Y1     27262976           // bf16 [BATCH][H1D]         8,388,608
#define WS_Y2     35651584           // f32  [BATCH][H2D]         8,388,608
#define WS_FM     44040192           // f32  [BATCH]                 65,536
#define WS_W1T    44105728           // bf16 [H1D][DIN]             425,984
#define WS_W2T    44531712           // bf16 [H2D][H1D]              65,536
#define WS_S1     44597248           // f32  [2][H1D]                 2,048
#define WS_S2     44599296           // f32  [2][H2D]                 1,024

#define GATHER_BLOCKS 2048           // BATCH/8
#define CONV_BLOCKS   961            // ceil((DIN*H1D + H1D*H2D)/256)

// ---------------------------------------------------------------------------
// Fused: gather embeddings -> X (bf16) + FM logit  |  weight transpose+cvt.
// Blocks [0,2048): gather (32 lanes/row, 2 rows/wave, 8 rows/block).
// Blocks [2048,3009): W1 -> bf16 W1^T, W2 -> bf16 W2^T.
__global__ __launch_bounds__(256) void k_gather_fm_conv(
    const int* __restrict__ xc, const float* __restrict__ lin,
    const float* __restrict__ lat, const float* __restrict__ bias,
    const float* __restrict__ W1, const float* __restrict__ W2,
    __bf16* __restrict__ X, float* __restrict__ fm,
    __bf16* __restrict__ W1T, __bf16* __restrict__ W2T) {
  const int tid = threadIdx.x;

  if (blockIdx.x >= GATHER_BLOCKS) {           // ---- convert part
    int i = (blockIdx.x - GATHER_BLOCKS) * 256 + tid;
    if (i < DIN * H1D) {                       // read coalesced, 2B scatter
      int c = i & (H1D - 1);
      int k = i >> 8;
      W1T[c * DIN + k] = (__bf16)W1[i];
    }
    int j = i - DIN * H1D;
    if (j >= 0 && j < H1D * H2D) {
      int c = j & (H2D - 1);
      int k = j >> 7;
      W2T[c * H1D + k] = (__bf16)W2[j];
    }
    return;
  }

  // ---- gather + FM part
  const int lane = tid & 63;
  const int wv   = tid >> 6;
  const int sub  = lane >> 5;
  const int d    = lane & 31;
  const int row  = blockIdx.x * 8 + wv * 2 + sub;

  int myidx = 0;
  float linv = 0.f;
  if (d < NF) {
    myidx = xc[row * NF + d];
    linv  = lin[(size_t)d * VOCAB + myidx];
  }

  float s = 0.f, ssq = 0.f;
  __bf16* xrow = X + (size_t)row * DIN;
  #pragma unroll
  for (int f = 0; f < NF; ++f) {
    int idx = __shfl(myidx, f, 32);
    float v = lat[((size_t)f * VOCAB + idx) * EDIM + d];
    s += v; ssq += v * v;
    xrow[f * EDIM + d] = (__bf16)v;
  }
  float sq = s * s;
  #pragma unroll
  for (int off = 16; off > 0; off >>= 1) {
    sq   += __shfl_down(sq,   off, 32);
    ssq  += __shfl_down(ssq,  off, 32);
    linv += __shfl_down(linv, off, 32);
  }
  if (d == 0) fm[row] = linv + 0.5f * (sq - ssq) + bias[0];
}

// ---------------------------------------------------------------------------
// GEMM1: Y1(bf16) = X(bf16) @ W1 (b1 cancels in BN).  Fused BN batch stats.
// Block: 256 thr (4 waves). Tile 128(M) x 64(N). K=832 staged in 2 LDS chunks.
// LDS row stride = 896 B (56 slots, mult of 8) so XOR swizzle stays in-row.
// XCD swizzle (T1): the 4 N-blocks of one M-tile land on one XCD -> X L2-hot.
#define G1_STRIDE 896
__global__ __launch_bounds__(256) void k_gemm1(
    const __bf16* __restrict__ X, const __bf16* __restrict__ W1T,
    __bf16* __restrict__ Y1, float* __restrict__ stats1) {
  __shared__ char  ldsW[64 * G1_STRIDE];   // 57,344 B
  __shared__ float redsum[64], redsq[64];

  const int tid  = threadIdx.x;
  const int lane = tid & 63;
  const int wv   = tid >> 6;
  const int swz  = (blockIdx.x & 7) * 64 + (blockIdx.x >> 3);   // bijective, 512=8*64
  const int mb   = swz >> 2;
  const int nb   = swz & 3;
  const int l15  = lane & 15;
  const int lq   = lane >> 4;

  f32x4 acc[2][4] = {};
  const int rowbase = mb * 128 + wv * 32;

  for (int ch = 0; ch < 2; ++ch) {
    __syncthreads();
    // stage W1T cols [nb*64,+64), k [ch*416,+416) with XOR swizzle (G4)
    #pragma unroll
    for (int it = 0; it < 13; ++it) {
      int lid = it * 256 + tid;          // 0..3327
      int c   = lid / 52;
      int kc  = lid - c * 52;
      const uint4* src = (const uint4*)(W1T + (size_t)(nb * 64 + c) * DIN + ch * 416);
      int byte = (c * G1_STRIDE + kc * 16) ^ ((c & 7) << 4);
      *(uint4*)(ldsW + byte) = src[kc];
    }
    __syncthreads();

    for (int kk = 0; kk < 13; ++kk) {
      const int kloc = kk * 32 + lq * 8;      // k within chunk
      bf16x8 a[2];
      #pragma unroll
      for (int i = 0; i < 2; ++i)
        a[i] = *(const bf16x8*)(X + (size_t)(rowbase + i * 16 + l15) * DIN
                                  + ch * 416 + kloc);
      #pragma unroll
      for (int j = 0; j < 4; ++j) {
        int c = j * 16 + l15;
        int byte = (c * G1_STRIDE + (kloc << 1)) ^ ((c & 7) << 4);
        bf16x8 b = *(const bf16x8*)(ldsW + byte);
        acc[0][j] = __builtin_amdgcn_mfma_f32_16x16x32_bf16(a[0], b, acc[0][j], 0, 0, 0);
        acc[1][j] = __builtin_amdgcn_mfma_f32_16x16x32_bf16(a[1], b, acc[1][j], 0, 0, 0);
      }
    }
  }

  // epilogue: write Y1 bf16 (C layout: col=lane&15, row=(lane>>4)*4+reg — m89)
  const int colbase = nb * 64;
  #pragma unroll
  for (int i = 0; i < 2; ++i) {
    int r0 = rowbase + i * 16 + lq * 4;
    #pragma unroll
    for (int j = 0; j < 4; ++j) {
      int c = colbase + j * 16 + l15;
      #pragma unroll
      for (int r = 0; r < 4; ++r)
        Y1[(size_t)(r0 + r) * H1D + c] = (__bf16)acc[i][j][r];
    }
  }
  // BN batch statistics (sum, sumsq per column) from f32 accumulators
  __syncthreads();
  if (tid < 64) { redsum[tid] = 0.f; redsq[tid] = 0.f; }
  __syncthreads();
  #pragma unroll
  for (int j = 0; j < 4; ++j) {
    float s = 0.f, q = 0.f;
    #pragma unroll
    for (int i = 0; i < 2; ++i)
      #pragma unroll
      for (int r = 0; r < 4; ++r) { float v = acc[i][j][r]; s += v; q += v * v; }
    atomicAdd(&redsum[j * 16 + l15], s);
    atomicAdd(&redsq [j * 16 + l15], q);
  }
  __syncthreads();
  if (tid < 64) {
    atomicAdd(&stats1[colbase + tid],        redsum[tid]);
    atomicAdd(&stats1[H1D + colbase + tid],  redsq[tid]);
  }
}

// ---------------------------------------------------------------------------
// GEMM2: Y2 = relu(BN1(Y1)) @ W2, BN1 fused into A-load. Fused BN2 stats.
__global__ __launch_bounds__(256) void k_gemm2(
    const __bf16* __restrict__ Y1, const __bf16* __restrict__ W2T,
    const float* __restrict__ stats1, const float* __restrict__ g1,
    const float* __restrict__ be1,
    float* __restrict__ Y2, float* __restrict__ stats2) {
  __shared__ char  ldsW[64 * 512];      // 64 cols x 256 k x 2B
  __shared__ float scL[H1D], shL[H1D];
  __shared__ float redsum[64], redsq[64];

  const int tid  = threadIdx.x;
  const int lane = tid & 63;
  const int wv   = tid >> 6;
  const int swz  = (blockIdx.x & 7) * 32 + (blockIdx.x >> 3);   // bijective, 256=8*32
  const int mb   = swz >> 1;
  const int nb   = swz & 1;
  const int l15  = lane & 15;
  const int lq   = lane >> 4;

  {  // BN1 affine params per k (column of Y1)
    float s = stats1[tid], q = stats1[H1D + tid];
    float m = s * (1.f / BATCH);
    float v = q * (1.f / BATCH) - m * m;
    float sc = g1[tid] * rsqrtf(v + BN_EPS);
    scL[tid] = sc;
    shL[tid] = be1[tid] - m * sc;
  }
  #pragma unroll
  for (int it = 0; it < 8; ++it) {
    int lid = it * 256 + tid;
    int c   = lid >> 5;
    int kc  = lid & 31;
    const uint4* src = (const uint4*)(W2T + (size_t)(nb * 64 + c) * H1D);
    int byte = (c * 512 + kc * 16) ^ ((c & 7) << 4);
    *(uint4*)(ldsW + byte) = src[kc];
  }
  __syncthreads();

  f32x4 acc[2][4] = {};
  const int rowbase = mb * 128 + wv * 32;

  for (int kk = 0; kk < 8; ++kk) {
    const int k0 = kk * 32 + lq * 8;
    f32x4 sc0 = *(const f32x4*)&scL[k0];
    f32x4 sc1 = *(const f32x4*)&scL[k0 + 4];
    f32x4 sh0 = *(const f32x4*)&shL[k0];
    f32x4 sh1 = *(const f32x4*)&shL[k0 + 4];
    bf16x8 a[2];
    #pragma unroll
    for (int i = 0; i < 2; ++i) {
      bf16x8 y = *(const bf16x8*)(Y1 + (size_t)(rowbase + i * 16 + l15) * H1D + k0);
      bf16x8 av;
      #pragma unroll
      for (int e = 0; e < 4; ++e) {
        av[e]     = (__bf16)fmaxf((float)y[e]     * sc0[e] + sh0[e], 0.f);
        av[e + 4] = (__bf16)fmaxf((float)y[e + 4] * sc1[e] + sh1[e], 0.f);
      }
      a[i] = av;
    }
    #pragma unroll
    for (int j = 0; j < 4; ++j) {
      int c = j * 16 + l15;
      int byte = (c * 512 + (k0 << 1)) ^ ((c & 7) << 4);
      bf16x8 b = *(const bf16x8*)(ldsW + byte);
      acc[0][j] = __builtin_amdgcn_mfma_f32_16x16x32_bf16(a[0], b, acc[0][j], 0, 0, 0);
      acc[1][j] = __builtin_amdgcn_mfma_f32_16x16x32_bf16(a[1], b, acc[1][j], 0, 0, 0);
    }
  }

  const int colbase = nb * 64;
  #pragma unroll
  for (int i = 0; i < 2; ++i) {
    int r0 = rowbase + i * 16 + lq * 4;
    #pragma unroll
    for (int j = 0; j < 4; ++j) {
      int c = colbase + j * 16 + l15;
      #pragma unroll
      for (int r = 0; r < 4; ++r)
        Y2[(size_t)(r0 + r) * H2D + c] = acc[i][j][r];
    }
  }
  __syncthreads();
  if (tid < 64) { redsum[tid] = 0.f; redsq[tid] = 0.f; }
  __syncthreads();
  #pragma unroll
  for (int j = 0; j < 4; ++j) {
    float s = 0.f, q = 0.f;
    #pragma unroll
    for (int i = 0; i < 2; ++i)
      #pragma unroll
      for (int r = 0; r < 4; ++r) { float v = acc[i][j][r]; s += v; q += v * v; }
    atomicAdd(&redsum[j * 16 + l15], s);
    atomicAdd(&redsq [j * 16 + l15], q);
  }
  __syncthreads();
  if (tid < 64) {
    atomicAdd(&stats2[colbase + tid],        redsum[tid]);
    atomicAdd(&stats2[H2D + colbase + tid],  redsq[tid]);
  }
}

// ---------------------------------------------------------------------------
// Final: out = fm + relu(BN2(Y2)) @ W3 + b3.  1 wave per row-iter, lane=2 cols.
__global__ __launch_bounds__(256) void k_final(
    const float* __restrict__ Y2, const float* __restrict__ stats2,
    const float* __restrict__ g2, const float* __restrict__ be2,
    const float* __restrict__ W3, const float* __restrict__ b3,
    const float* __restrict__ fm, float* __restrict__ out) {
  const int tid  = threadIdx.x;
  const int lane = tid & 63;
  const int wv   = tid >> 6;
  const int k0   = lane * 2;

  float s0 = stats2[k0],     q0 = stats2[H2D + k0];
  float s1 = stats2[k0 + 1], q1 = stats2[H2D + k0 + 1];
  float m0 = s0 * (1.f / BATCH), m1 = s1 * (1.f / BATCH);
  float v0 = q0 * (1.f / BATCH) - m0 * m0;
  float v1 = q1 * (1.f / BATCH) - m1 * m1;
  float sc0 = g2[k0]     * rsqrtf(v0 + BN_EPS);
  float sc1 = g2[k0 + 1] * rsqrtf(v1 + BN_EPS);
  float sh0 = be2[k0]     - m0 * sc0;
  float sh1 = be2[k0 + 1] - m1 * sc1;
  float w30 = W3[k0], w31 = W3[k0 + 1];
  float bb  = b3[0];

  const int rbase = blockIdx.x * 64 + wv * 16;
  for (int it = 0; it < 16; ++it) {
    int row = rbase + it;
    float2 y = *(const float2*)(Y2 + (size_t)row * H2D + k0);
    float h0 = fmaxf(y.x * sc0 + sh0, 0.f);
    float h1 = fmaxf(y.y * sc1 + sh1, 0.f);
    float p  = h0 * w30 + h1 * w31;
    #pragma unroll
    for (int off = 32; off > 0; off >>= 1) p += __shfl_xor(p, off);
    if (lane == 0) out[row] = fm[row] + p + bb;
  }
}

// ---------------------------------------------------------------------------
extern "C" void kernel_launch(void* const* d_in, const int* in_sizes, int n_in,
                              void* d_out, int out_size, void* d_ws, size_t ws_size,
                              hipStream_t stream) {
  const int*   xc   = (const int*)  d_in[0];
  const float* lin  = (const float*)d_in[1];
  const float* lat  = (const float*)d_in[2];
  const float* W1   = (const float*)d_in[3];
  // d_in[4] = b1: cancels inside BatchNorm (mean-subtracted) — unused
  const float* g1   = (const float*)d_in[5];
  const float* be1  = (const float*)d_in[6];
  const float* W2   = (const float*)d_in[7];
  // d_in[8] = b2: cancels — unused
  const float* g2   = (const float*)d_in[9];
  const float* be2  = (const float*)d_in[10];
  const float* W3   = (const float*)d_in[11];
  const float* b3   = (const float*)d_in[12];
  const float* bias = (const float*)d_in[13];

  char* ws = (char*)d_ws;
  __bf16* X   = (__bf16*)(ws + WS_X);
  __bf16* Y1  = (__bf16*)(ws + WS_Y1);
  float*  Y2  = (float*) (ws + WS_Y2);
  float*  fmv = (float*) (ws + WS_FM);
  __bf16* W1T = (__bf16*)(ws + WS_W1T);
  __bf16* W2T = (__bf16*)(ws + WS_W2T);
  float*  S1  = (float*) (ws + WS_S1);
  float*  S2  = (float*) (ws + WS_S2);
  float*  outp = (float*)d_out;

  // zero BN stats (S1,S2 contiguous: 2*256 + 2*128 floats)
  hipMemsetAsync(S1, 0, (2 * H1D + 2 * H2D) * sizeof(float), stream);

  k_gather_fm_conv<<<dim3(GATHER_BLOCKS + CONV_BLOCKS), dim3(256), 0, stream>>>(
      xc, lin, lat, bias, W1, W2, X, fmv, W1T, W2T);
  k_gemm1 <<<dim3(512), dim3(256), 0, stream>>>(X, W1T, Y1, S1);
  k_gemm2 <<<dim3(256), dim3(256), 0, stream>>>(Y1, W2T, S1, g1, be1, Y2, S2);
  k_final <<<dim3(256), dim3(256), 0, stream>>>(Y2, S2, g2, be2, W3, b3, fmv, outp);
}

// Round 4
// 456.718 us; speedup vs baseline: 1.0179x; 1.0004x over previous
//
#include <hip/hip_runtime.h>
#include <hip/hip_bf16.h>

#define BATCH   16384
#define NF      26
#define EDIM    32
#define DIN     832     // NF*EDIM
#define H1D     256
#define H2D     128
#define VOCAB   100000
#define BN_EPS  1e-5f

typedef float  f32x4  __attribute__((ext_vector_type(4)));
typedef __bf16 bf16x2 __attribute__((ext_vector_type(2)));
typedef __bf16 bf16x4 __attribute__((ext_vector_type(4)));
typedef __bf16 bf16x8 __attribute__((ext_vector_type(8)));

// workspace layout (bytes) — X eliminated (fused); Y2 now bf16
#define WS_Y1     0                  // bf16 [BATCH][H1D]         8,388,608
#define WS_Y2     8388608            // bf16 [BATCH][H2D]         4,194,304
#define WS_FM     12582912           // f32  [BATCH]                 65,536
#define WS_W1T    12648448           // bf16 [H1D][DIN]             425,984
#define WS_W2T    13074432           // bf16 [H2D][H1D]              65,536
#define WS_S1     13139968           // f32  [2][H1D]                 2,048
#define WS_S2     13142016           // f32  [2][H2D]                 1,024

// ---------------------------------------------------------------------------
// Prep: W1 -> bf16 W1^T [256][832], W2 -> bf16 W2^T [128][256]; zero BN stats.
__global__ __launch_bounds__(256) void k_prep(const float* __restrict__ W1,
                                              const float* __restrict__ W2,
                                              __bf16* __restrict__ W1T,
                                              __bf16* __restrict__ W2T,
                                              float* __restrict__ stats) {
  int i = blockIdx.x * 256 + threadIdx.x;
  if (i < DIN * H1D) {                // read coalesced, scatter 2B writes
    int c = i & (H1D - 1);
    int k = i >> 8;
    W1T[c * DIN + k] = (__bf16)W1[i];
  }
  int j = i - DIN * H1D;
  if (j >= 0 && j < H1D * H2D) {
    int c = j & (H2D - 1);
    int k = j >> 7;
    W2T[c * H1D + k] = (__bf16)W2[j];
  }
  if (blockIdx.x == 0) {              // zero S1 (512 f32) + S2 (256 f32)
    stats[threadIdx.x] = 0.f;
    stats[threadIdx.x + 256] = 0.f;
    stats[threadIdx.x + 512] = 0.f;
  }
}

// ---------------------------------------------------------------------------
// Fused: gather 64 rows of embeddings into LDS (bf16, swizzled) + FM logit
//        + GEMM1 (Y1 = X @ W1, b1 cancels in BN) + BN1 batch stats.
// Grid 256 blocks (1/CU), 256 thr (4 waves). M=64, N=256 (full), K=832.
// X-tile: 64 rows x 1664 B (104 slots of 16 B; XOR slot^=(row&7) — bijective,
// 104 % 8 == 0). W-tile: 256 cols x 128 B (8 slots; XOR slot^=(col&7)).
#define XROW 1664
__global__ __launch_bounds__(256) void k_fused1(
    const int* __restrict__ xc, const float* __restrict__ lin,
    const float* __restrict__ lat, const float* __restrict__ bias,
    const __bf16* __restrict__ W1T,
    __bf16* __restrict__ Y1, float* __restrict__ fm,
    float* __restrict__ stats1) {
  __shared__ char  Xt[64 * XROW];      // 106,496 B
  __shared__ char  Wt[256 * 128];      //  32,768 B
  __shared__ float redsum[256], redsq[256];

  const int tid  = threadIdx.x;
  const int lane = tid & 63;
  const int wv   = tid >> 6;
  const int l15  = lane & 15;
  const int lq   = lane >> 4;
  const int blk  = blockIdx.x;

  redsum[tid] = 0.f; redsq[tid] = 0.f;   // used only after GEMM (no race)

  // ---- stage W chunk 0 (overlaps gather latency) ----
  {
    #pragma unroll
    for (int it = 0; it < 8; ++it) {
      int lid = it * 256 + tid;          // 2048 slots
      int c = lid >> 3, s = lid & 7;
      bf16x8 w = *(const bf16x8*)(W1T + (size_t)c * DIN + s * 8);
      *(bf16x8*)(Wt + c * 128 + ((s ^ (c & 7)) << 4)) = w;
    }
  }

  // ---- gather: 1664 (row,field) pairs; 8-lane group per pair, 16B/lane ----
  {
    const int G = tid >> 3, e = tid & 7;
    #pragma unroll
    for (int o = 0; o < 4; ++o) {
      int idxv[13], rv[13], fv[13];
      #pragma unroll
      for (int j = 0; j < 13; ++j) {
        int p = (o * 13 + j) * 32 + G;   // 0..1663 == row*26+f
        int r = p / 26;
        rv[j] = r; fv[j] = p - r * 26;
        idxv[j] = xc[blk * (64 * NF) + p];
      }
      #pragma unroll
      for (int j = 0; j < 13; ++j) {
        f32x4 v = *(const f32x4*)(lat + ((size_t)fv[j] * VOCAB + idxv[j]) * EDIM + e * 4);
        bf16x4 b;
        #pragma unroll
        for (int q = 0; q < 4; ++q) b[q] = (__bf16)v[q];
        int slot = fv[j] * 4 + (e >> 1);
        int byte = rv[j] * XROW + (((slot ^ (rv[j] & 7)) << 4)) + (e & 1) * 8;
        *(bf16x4*)(Xt + byte) = b;
      }
    }
  }
  __syncthreads();

  // ---- FM from LDS tile: thread = (row r, dim-group dg of 8) ----
  {
    const int r  = tid >> 2;
    const int dg = tid & 3;
    float s8[8] = {}; float ssq = 0.f;
    #pragma unroll
    for (int f = 0; f < NF; ++f) {
      int byte = r * XROW + (((f * 4 + dg) ^ (r & 7)) << 4);
      bf16x8 v = *(const bf16x8*)(Xt + byte);
      #pragma unroll
      for (int q = 0; q < 8; ++q) {
        float x = (float)v[q];
        s8[q] += x; ssq += x * x;
      }
    }
    float sq = 0.f;
    #pragma unroll
    for (int q = 0; q < 8; ++q) sq += s8[q] * s8[q];
    float linv = 0.f;
    #pragma unroll
    for (int f = dg; f < NF; f += 4) {
      int idx = xc[blk * (64 * NF) + r * NF + f];
      linv += lin[(size_t)f * VOCAB + idx];
    }
    float red = 0.5f * (sq - ssq) + linv;
    red += __shfl_xor(red, 1);
    red += __shfl_xor(red, 2);
    if (dg == 0) fm[blk * 64 + r] = red + bias[0];
  }

  // ---- GEMM: 13 K-chunks of 64; wave wv owns cols [wv*64, +64) ----
  f32x4 acc[4][4] = {};
  for (int ch = 0; ch < 13; ++ch) {
    if (ch) {
      __syncthreads();
      #pragma unroll
      for (int it = 0; it < 8; ++it) {
        int lid = it * 256 + tid;
        int c = lid >> 3, s = lid & 7;
        bf16x8 w = *(const bf16x8*)(W1T + (size_t)c * DIN + ch * 64 + s * 8);
        *(bf16x8*)(Wt + c * 128 + ((s ^ (c & 7)) << 4)) = w;
      }
      __syncthreads();
    }
    #pragma unroll
    for (int kk = 0; kk < 64; kk += 32) {
      bf16x8 a[4], b[4];
      #pragma unroll
      for (int mf = 0; mf < 4; ++mf) {
        int row  = mf * 16 + l15;
        int slot = ch * 8 + (kk >> 3) + lq;
        a[mf] = *(const bf16x8*)(Xt + row * XROW + ((slot ^ (row & 7)) << 4));
      }
      #pragma unroll
      for (int nf = 0; nf < 4; ++nf) {
        int c    = wv * 64 + nf * 16 + l15;
        int slot = (kk >> 3) + lq;
        b[nf] = *(const bf16x8*)(Wt + c * 128 + ((slot ^ (c & 7)) << 4));
      }
      #pragma unroll
      for (int mf = 0; mf < 4; ++mf)
        #pragma unroll
        for (int nf = 0; nf < 4; ++nf)
          acc[mf][nf] = __builtin_amdgcn_mfma_f32_16x16x32_bf16(a[mf], b[nf], acc[mf][nf], 0, 0, 0);
    }
  }

  // ---- epilogue: Y1 bf16 (C layout: col=lane&15, row=(lane>>4)*4+reg) ----
  #pragma unroll
  for (int mf = 0; mf < 4; ++mf) {
    int r0 = blk * 64 + mf * 16 + lq * 4;
    #pragma unroll
    for (int nf = 0; nf < 4; ++nf) {
      int c = wv * 64 + nf * 16 + l15;
      #pragma unroll
      for (int r = 0; r < 4; ++r)
        Y1[(size_t)(r0 + r) * H1D + c] = (__bf16)acc[mf][nf][r];
    }
  }
  // ---- BN1 stats from f32 accumulators ----
  #pragma unroll
  for (int nf = 0; nf < 4; ++nf) {
    float s = 0.f, q = 0.f;
    #pragma unroll
    for (int mf = 0; mf < 4; ++mf)
      #pragma unroll
      for (int r = 0; r < 4; ++r) { float v = acc[mf][nf][r]; s += v; q += v * v; }
    atomicAdd(&redsum[wv * 64 + nf * 16 + l15], s);
    atomicAdd(&redsq [wv * 64 + nf * 16 + l15], q);
  }
  __syncthreads();
  atomicAdd(&stats1[tid],       redsum[tid]);
  atomicAdd(&stats1[H1D + tid], redsq[tid]);
}

// ---------------------------------------------------------------------------
// GEMM2: Y2(bf16) = relu(BN1(Y1)) @ W2, BN1 fused into A-load. BN2 stats.
__global__ __launch_bounds__(256) void k_gemm2(
    const __bf16* __restrict__ Y1, const __bf16* __restrict__ W2T,
    const float* __restrict__ stats1, const float* __restrict__ g1,
    const float* __restrict__ be1,
    __bf16* __restrict__ Y2, float* __restrict__ stats2) {
  __shared__ char  ldsW[64 * 512];      // 64 cols x 256 k x 2B
  __shared__ float scL[H1D], shL[H1D];
  __shared__ float redsum[64], redsq[64];

  const int tid  = threadIdx.x;
  const int lane = tid & 63;
  const int wv   = tid >> 6;
  const int swz  = (blockIdx.x & 7) * 32 + (blockIdx.x >> 3);   // bijective, 256=8*32
  const int mb   = swz >> 1;
  const int nb   = swz & 1;
  const int l15  = lane & 15;
  const int lq   = lane >> 4;

  {  // BN1 affine params per k (column of Y1)
    float s = stats1[tid], q = stats1[H1D + tid];
    float m = s * (1.f / BATCH);
    float v = q * (1.f / BATCH) - m * m;
    float sc = g1[tid] * rsqrtf(v + BN_EPS);
    scL[tid] = sc;
    shL[tid] = be1[tid] - m * sc;
  }
  #pragma unroll
  for (int it = 0; it < 8; ++it) {
    int lid = it * 256 + tid;
    int c   = lid >> 5;
    int kc  = lid & 31;
    const uint4* src = (const uint4*)(W2T + (size_t)(nb * 64 + c) * H1D);
    int byte = (c * 512 + kc * 16) ^ ((c & 7) << 4);
    *(uint4*)(ldsW + byte) = src[kc];
  }
  __syncthreads();

  f32x4 acc[2][4] = {};
  const int rowbase = mb * 128 + wv * 32;

  for (int kk = 0; kk < 8; ++kk) {
    const int k0 = kk * 32 + lq * 8;
    f32x4 sc0 = *(const f32x4*)&scL[k0];
    f32x4 sc1 = *(const f32x4*)&scL[k0 + 4];
    f32x4 sh0 = *(const f32x4*)&shL[k0];
    f32x4 sh1 = *(const f32x4*)&shL[k0 + 4];
    bf16x8 a[2];
    #pragma unroll
    for (int i = 0; i < 2; ++i) {
      bf16x8 y = *(const bf16x8*)(Y1 + (size_t)(rowbase + i * 16 + l15) * H1D + k0);
      bf16x8 av;
      #pragma unroll
      for (int e = 0; e < 4; ++e) {
        av[e]     = (__bf16)fmaxf((float)y[e]     * sc0[e] + sh0[e], 0.f);
        av[e + 4] = (__bf16)fmaxf((float)y[e + 4] * sc1[e] + sh1[e], 0.f);
      }
      a[i] = av;
    }
    #pragma unroll
    for (int j = 0; j < 4; ++j) {
      int c = j * 16 + l15;
      int byte = (c * 512 + (k0 << 1)) ^ ((c & 7) << 4);
      bf16x8 b = *(const bf16x8*)(ldsW + byte);
      acc[0][j] = __builtin_amdgcn_mfma_f32_16x16x32_bf16(a[0], b, acc[0][j], 0, 0, 0);
      acc[1][j] = __builtin_amdgcn_mfma_f32_16x16x32_bf16(a[1], b, acc[1][j], 0, 0, 0);
    }
  }

  const int colbase = nb * 64;
  #pragma unroll
  for (int i = 0; i < 2; ++i) {
    int r0 = rowbase + i * 16 + lq * 4;
    #pragma unroll
    for (int j = 0; j < 4; ++j) {
      int c = colbase + j * 16 + l15;
      #pragma unroll
      for (int r = 0; r < 4; ++r)
        Y2[(size_t)(r0 + r) * H2D + c] = (__bf16)acc[i][j][r];
    }
  }
  __syncthreads();
  if (tid < 64) { redsum[tid] = 0.f; redsq[tid] = 0.f; }
  __syncthreads();
  #pragma unroll
  for (int j = 0; j < 4; ++j) {
    float s = 0.f, q = 0.f;
    #pragma unroll
    for (int i = 0; i < 2; ++i)
      #pragma unroll
      for (int r = 0; r < 4; ++r) { float v = acc[i][j][r]; s += v; q += v * v; }
    atomicAdd(&redsum[j * 16 + l15], s);
    atomicAdd(&redsq [j * 16 + l15], q);
  }
  __syncthreads();
  if (tid < 64) {
    atomicAdd(&stats2[colbase + tid],        redsum[tid]);
    atomicAdd(&stats2[H2D + colbase + tid],  redsq[tid]);
  }
}

// ---------------------------------------------------------------------------
// Final: out = fm + relu(BN2(Y2)) @ W3 + b3.  1 wave per row-iter, lane=2 cols.
__global__ __launch_bounds__(256) void k_final(
    const __bf16* __restrict__ Y2, const float* __restrict__ stats2,
    const float* __restrict__ g2, const float* __restrict__ be2,
    const float* __restrict__ W3, const float* __restrict__ b3,
    const float* __restrict__ fm, float* __restrict__ out) {
  const int tid  = threadIdx.x;
  const int lane = tid & 63;
  const int wv   = tid >> 6;
  const int k0   = lane * 2;

  float s0 = stats2[k0],     q0 = stats2[H2D + k0];
  float s1 = stats2[k0 + 1], q1 = stats2[H2D + k0 + 1];
  float m0 = s0 * (1.f / BATCH), m1 = s1 * (1.f / BATCH);
  float v0 = q0 * (1.f / BATCH) - m0 * m0;
  float v1 = q1 * (1.f / BATCH) - m1 * m1;
  float sc0 = g2[k0]     * rsqrtf(v0 + BN_EPS);
  float sc1 = g2[k0 + 1] * rsqrtf(v1 + BN_EPS);
  float sh0 = be2[k0]     - m0 * sc0;
  float sh1 = be2[k0 + 1] - m1 * sc1;
  float w30 = W3[k0], w31 = W3[k0 + 1];
  float bb  = b3[0];

  const int rbase = blockIdx.x * 64 + wv * 16;
  for (int it = 0; it < 16; ++it) {
    int row = rbase + it;
    bf16x2 y = *(const bf16x2*)(Y2 + (size_t)row * H2D + k0);
    float h0 = fmaxf((float)y[0] * sc0 + sh0, 0.f);
    float h1 = fmaxf((float)y[1] * sc1 + sh1, 0.f);
    float p  = h0 * w30 + h1 * w31;
    #pragma unroll
    for (int off = 32; off > 0; off >>= 1) p += __shfl_xor(p, off);
    if (lane == 0) out[row] = fm[row] + p + bb;
  }
}

// ---------------------------------------------------------------------------
extern "C" void kernel_launch(void* const* d_in, const int* in_sizes, int n_in,
                              void* d_out, int out_size, void* d_ws, size_t ws_size,
                              hipStream_t stream) {
  const int*   xc   = (const int*)  d_in[0];
  const float* lin  = (const float*)d_in[1];
  const float* lat  = (const float*)d_in[2];
  const float* W1   = (const float*)d_in[3];
  // d_in[4] = b1: cancels inside BatchNorm (mean-subtracted) — unused
  const float* g1   = (const float*)d_in[5];
  const float* be1  = (const float*)d_in[6];
  const float* W2   = (const float*)d_in[7];
  // d_in[8] = b2: cancels — unused
  const float* g2   = (const float*)d_in[9];
  const float* be2  = (const float*)d_in[10];
  const float* W3   = (const float*)d_in[11];
  const float* b3   = (const float*)d_in[12];
  const float* bias = (const float*)d_in[13];

  char* ws = (char*)d_ws;
  __bf16* Y1  = (__bf16*)(ws + WS_Y1);
  __bf16* Y2  = (__bf16*)(ws + WS_Y2);
  float*  fmv = (float*) (ws + WS_FM);
  __bf16* W1T = (__bf16*)(ws + WS_W1T);
  __bf16* W2T = (__bf16*)(ws + WS_W2T);
  float*  S1  = (float*) (ws + WS_S1);
  float*  S2  = (float*) (ws + WS_S2);
  float*  outp = (float*)d_out;

  k_prep  <<<dim3(961), dim3(256), 0, stream>>>(W1, W2, W1T, W2T, S1);
  k_fused1<<<dim3(256), dim3(256), 0, stream>>>(xc, lin, lat, bias, W1T, Y1, fmv, S1);
  k_gemm2 <<<dim3(256), dim3(256), 0, stream>>>(Y1, W2T, S1, g1, be1, Y2, S2);
  k_final <<<dim3(256), dim3(256), 0, stream>>>(Y2, S2, g2, be2, W3, b3, fmv, outp);
}